// Round 12
// baseline (96.998 us; speedup 1.0000x reference)
//
#include <hip/hip_runtime.h>

#define CLS   160          // CLASS_NUM * NUM_PRED
#define TOPKN 1000
#define N0 147456
#define N1 36864
#define N2 9216
#define N3 2304
#define N4 576
#define NROWS (N0 + N1 + N2 + N3)
#define BD1 N0
#define BD2 (N0 + N1)
#define BD3 (N0 + N1 + N2)
#define NSEL (4 * TOPKN + N4)
#define NBINS 65536
#define CAND_CAP 2048

__device__ __forceinline__ unsigned sortable(float f) {
    unsigned u = __float_as_uint(f);
    return (u & 0x80000000u) ? ~u : (u | 0x80000000u);
}

// ---------------------------------------------------------------------------
// K1: ruler keys (proven R4-R6). Zeroes hist|coarse (contiguous).
// ---------------------------------------------------------------------------
__global__ __launch_bounds__(256) void k_ruler(
    const float* __restrict__ c0, const float* __restrict__ c1,
    const float* __restrict__ c2, const float* __restrict__ c3,
    unsigned* __restrict__ keys, unsigned* __restrict__ hist)
{
    int tid = blockIdx.x * 256 + threadIdx.x;
    if (tid < 4 * NBINS + 4096) hist[tid] = 0;

    int r0 = blockIdx.x << 7;
    const float* cb; int lr0;
    if (r0 < BD1)      { cb = c0; lr0 = r0; }
    else if (r0 < BD2) { cb = c1; lr0 = r0 - BD1; }
    else if (r0 < BD3) { cb = c2; lr0 = r0 - BD2; }
    else               { cb = c3; lr0 = r0 - BD3; }

    int wv   = threadIdx.x >> 6;
    int lane = threadIdx.x & 63;
    int sub  = lane >> 3;
    int col  = lane & 7;
    #pragma unroll
    for (int i = 0; i < 4; ++i) {
        int rrel = wv * 32 + i * 8 + sub;
        const float4* p = (const float4*)cb + (size_t)(lr0 + rrel) * 40 + col;
        float m = -3.4e38f;
        #pragma unroll
        for (int k = 0; k < 5; ++k) {
            float4 v = p[8 * k];
            m = fmaxf(m, fmaxf(fmaxf(v.x, v.y), fmaxf(v.z, v.w)));
        }
        m = fmaxf(m, __shfl_xor(m, 1));
        m = fmaxf(m, __shfl_xor(m, 2));
        m = fmaxf(m, __shfl_xor(m, 4));
        if (col == 0) keys[r0 + rrel] = sortable(m);
    }
}

// ---------------------------------------------------------------------------
// K2: chunked segment histogram (proven R4/R6). 1024 blocks x 256.
// ---------------------------------------------------------------------------
__global__ __launch_bounds__(256) void k_hist(const unsigned* __restrict__ keys,
                                              unsigned* __restrict__ hist,
                                              unsigned* __restrict__ coarse)
{
    int b        = blockIdx.x;
    int level    = b >> 8;
    unsigned seg = (b >> 4) & 15;
    int chunk    = b & 15;
    __shared__ unsigned cnt[4096];
    for (int i = threadIdx.x; i < 4096; i += 256) cnt[i] = 0;
    __syncthreads();
    int base, n;
    switch (level) {
        case 0:  base = 0;   n = N0; break;
        case 1:  base = BD1; n = N1; break;
        case 2:  base = BD2; n = N2; break;
        default: base = BD3; n = N3; break;
    }
    int q = n >> 4;
    const uint4* kp = (const uint4*)(keys + base + chunk * q);
    int nv = q >> 2;
    for (int i = threadIdx.x; i < nv; i += 256) {
        uint4 k = kp[i];
        unsigned b0 = k.x >> 16, b1 = k.y >> 16, b2 = k.z >> 16, b3 = k.w >> 16;
        if ((b0 >> 12) == seg) atomicAdd(&cnt[b0 & 4095u], 1u);
        if ((b1 >> 12) == seg) atomicAdd(&cnt[b1 & 4095u], 1u);
        if ((b2 >> 12) == seg) atomicAdd(&cnt[b2 & 4095u], 1u);
        if ((b3 >> 12) == seg) atomicAdd(&cnt[b3 & 4095u], 1u);
    }
    __syncthreads();
    unsigned* h = hist + level * NBINS + (seg << 12);
    for (int i = threadIdx.x; i < 4096; i += 256) {
        unsigned c = cnt[i];
        if (c) atomicAdd(&h[i], c);
    }
    if (threadIdx.x < 64) {
        int j = threadIdx.x;
        unsigned s2 = 0;
        #pragma unroll 8
        for (int i = 0; i < 64; ++i) s2 += cnt[j * 64 + ((i + j) & 63)];
        if (s2) atomicAdd(&coarse[level * 1024 + (int)(seg << 6) + j], s2);
    }
}

// ---------------------------------------------------------------------------
// K3: fused decide+compact+rank, one block per level (R6 structure, 82.4us
// best). ONE change vs R6: part B batches 8 independent uint4 loads into
// STATICALLY-indexed registers before the ballot-append consumes them.
// R6's loop had load->ballot in the same iteration = 1 outstanding load per
// wave = chain of 36 remote-L2 latencies (~50us). Depth-8 MLP cuts the
// chain to ~5 latencies (~2us) + processing.
// ---------------------------------------------------------------------------
__global__ __launch_bounds__(1024) void k_select(const unsigned* __restrict__ keys,
                                                 const unsigned* __restrict__ hist,
                                                 const unsigned* __restrict__ coarse,
                                                 unsigned* __restrict__ sel)
{
    int level = blockIdx.x;
    int t     = threadIdx.x;
    int lane  = t & 63;

    __shared__ unsigned s[1024];
    __shared__ unsigned long long a[CAND_CAP];
    __shared__ unsigned thr_s, chunk_s, cum0_s, cnt_s;

    // ---- A: threshold from coarse + one 64-bin refine (proven R6 math) ----
    s[t] = coarse[level * 1024 + t];
    if (t == 0) cnt_s = 0;
    __syncthreads();
    for (int off = 1; off < 1024; off <<= 1) {
        unsigned v   = s[t];
        unsigned add = (t + off < 1024) ? s[t + off] : 0u;
        __syncthreads();
        s[t] = v + add;
        __syncthreads();
    }
    if (s[t] >= TOPKN && (t == 1023 || s[t + 1] < TOPKN)) {
        chunk_s = (unsigned)t;
        cum0_s  = (t == 1023) ? 0u : s[t + 1];
    }
    __syncthreads();
    if (t < 64) {
        const unsigned* h = hist + level * NBINS;
        unsigned c = h[chunk_s * 64 + (unsigned)t];
        unsigned suf = c;
        #pragma unroll
        for (int off = 1; off < 64; off <<= 1) {
            unsigned v = __shfl_down(suf, off);
            if (t + off < 64) suf += v;
        }
        unsigned long long mask = __ballot(cum0_s + suf >= TOPKN);
        if (t == 0)
            thr_s = ((chunk_s << 6) + (63u - (unsigned)__clzll(mask))) << 16;
    }
    __syncthreads();
    unsigned thr = thr_s;

    // ---- B: depth-8 batched scan + wave-aggregated ballot append ----
    int base = (level == 0) ? 0 : (level == 1) ? BD1 : (level == 2) ? BD2 : BD3;
    int n    = (level == 0) ? N0 : (level == 1) ? N1 : (level == 2) ? N2 : N3;
    const uint4* kp = (const uint4*)(keys + base);
    int nv = n >> 2;
    int nb = (nv + 8 * 1024 - 1) / (8 * 1024);
    for (int ib = 0; ib < nb; ++ib) {
        uint4 u0, u1, u2, u3, u4, u5, u6, u7;   // named regs: static indexing
        int i0 = ib * 8 * 1024 + t;
        const uint4 z = make_uint4(0u, 0u, 0u, 0u);
        u0 = (i0 + 0 * 1024 < nv) ? kp[i0 + 0 * 1024] : z;
        u1 = (i0 + 1 * 1024 < nv) ? kp[i0 + 1 * 1024] : z;
        u2 = (i0 + 2 * 1024 < nv) ? kp[i0 + 2 * 1024] : z;
        u3 = (i0 + 3 * 1024 < nv) ? kp[i0 + 3 * 1024] : z;
        u4 = (i0 + 4 * 1024 < nv) ? kp[i0 + 4 * 1024] : z;
        u5 = (i0 + 5 * 1024 < nv) ? kp[i0 + 5 * 1024] : z;
        u6 = (i0 + 6 * 1024 < nv) ? kp[i0 + 6 * 1024] : z;
        u7 = (i0 + 7 * 1024 < nv) ? kp[i0 + 7 * 1024] : z;
        #pragma unroll
        for (int j = 0; j < 8; ++j) {
            uint4 k4 = (j == 0) ? u0 : (j == 1) ? u1 : (j == 2) ? u2 :
                       (j == 3) ? u3 : (j == 4) ? u4 : (j == 5) ? u5 :
                       (j == 6) ? u6 : u7;
            int ii = i0 + j * 1024;          // element base index (uint4 units)
            unsigned kv[4] = {k4.x, k4.y, k4.z, k4.w};
            #pragma unroll
            for (int c = 0; c < 4; ++c) {
                bool pass = kv[c] >= thr;    // zero-fill never passes (thr>=2^31)
                unsigned long long mask = __ballot(pass);
                if (pass) {
                    int leader    = __ffsll((long long)mask) - 1;
                    unsigned tot  = (unsigned)__popcll(mask);
                    unsigned rank = (unsigned)__popcll(mask & ((1ull << lane) - 1ull));
                    unsigned bp = 0;
                    if (lane == leader) bp = atomicAdd(&cnt_s, tot);
                    bp = (unsigned)__shfl((int)bp, leader);
                    unsigned pos = bp + rank;
                    if (pos < CAND_CAP)
                        a[pos] = ((unsigned long long)kv[c] << 32) |
                                 (unsigned)~(unsigned)(4 * ii + c);
                }
            }
        }
    }
    __syncthreads();
    unsigned cnt = cnt_s;
    if (cnt > CAND_CAP) cnt = CAND_CAP;

    // ---- C: exact stable rank (descending key, ties ascending index) ----
    for (int i = t; i < (int)cnt; i += 1024) {
        unsigned long long mine = a[i];
        unsigned rank = 0;
        for (int j = 0; j < (int)cnt; ++j) rank += (a[j] > mine) ? 1u : 0u;
        if (rank < TOPKN)
            sel[level * TOPKN + rank] = ~(unsigned)(mine & 0xFFFFFFFFull);
    }
}

// ---------------------------------------------------------------------------
// K4: epilogue (proven R6, unchanged). One block per selected anchor.
// ---------------------------------------------------------------------------
__global__ __launch_bounds__(256) void k_epilogue(
    const float* a0, const float* a1, const float* a2, const float* a3, const float* a4,
    const float* c0, const float* c1, const float* c2, const float* c3, const float* c4,
    const float* r0, const float* r1, const float* r2, const float* r3, const float* r4,
    const unsigned* __restrict__ sel, float* __restrict__ out)
{
    int s = blockIdx.x;
    int level, idx;
    if (s < 4 * TOPKN) {
        level = s / TOPKN;
        idx   = (int)sel[s];
    } else {
        level = 4;
        idx   = s - 4 * TOPKN;
    }
    const float *A, *C, *R;
    switch (level) {
        case 0: A = a0; C = c0; R = r0; break;
        case 1: A = a1; C = c1; R = r1; break;
        case 2: A = a2; C = c2; R = r2; break;
        case 3: A = a3; C = c3; R = r3; break;
        default: A = a4; C = c4; R = r4; break;
    }

    __shared__ float sc[CLS];
    __shared__ float bb[8];

    const float* cp = C + (size_t)idx * CLS;
    if (threadIdx.x < CLS) {
        float x = cp[threadIdx.x];
        sc[threadIdx.x] = 1.0f / (1.0f + __expf(-x));
    }
    if (threadIdx.x == 192) {
        const float* ap = A + (size_t)idx * 4;
        const float* rp = R + (size_t)idx * 8;
        float x1 = ap[0], y1 = ap[1], x2 = ap[2], y2 = ap[3];
        float w  = x2 - x1 + 1.0f, h = y2 - y1 + 1.0f;
        float cx = x1 + 0.5f * w,  cy = y1 + 0.5f * h;
        #pragma unroll
        for (int p = 0; p < 2; ++p) {
            float pcx = cx + rp[4 * p + 0] * w;
            float pcy = cy + rp[4 * p + 1] * h;
            float pw  = w * __expf(rp[4 * p + 2]);
            float ph  = h * __expf(rp[4 * p + 3]);
            bb[4 * p + 0] = pcx - 0.5f * pw;
            bb[4 * p + 1] = pcy - 0.5f * ph;
            bb[4 * p + 2] = pcx + 0.5f * pw;
            bb[4 * p + 3] = pcy + 0.5f * ph;
        }
    }
    __syncthreads();

    float4* orow = (float4*)(out + (size_t)s * 960);
    if (threadIdx.x < 240) {
        int j = threadIdx.x / 3, part = threadIdx.x % 3;
        float tag = (float)(j + 1);
        float4 v;
        if (part == 0)      v = make_float4(bb[0], bb[1], bb[2], bb[3]);
        else if (part == 1) v = make_float4(sc[j], tag, bb[4], bb[5]);
        else                v = make_float4(bb[6], bb[7], sc[80 + j], tag);
        orow[threadIdx.x] = v;
    }
}

// ---------------------------------------------------------------------------
// Workspace (uint32 words):
//   keys[NROWS] | hist[4*NBINS] | coarse[4096] | sel[4*TOPKN]  (~1.8 MB)
// hist|coarse zeroed by k_ruler each call.
// ---------------------------------------------------------------------------
extern "C" void kernel_launch(void* const* d_in, const int* in_sizes, int n_in,
                              void* d_out, int out_size, void* d_ws, size_t ws_size,
                              hipStream_t stream)
{
    bool interleaved = (in_sizes[1] > 1000000);
    const float *A[5], *C[5], *R[5];
    for (int i = 0; i < 5; ++i) {
        if (interleaved) {
            A[i] = (const float*)d_in[3 * i + 0];
            C[i] = (const float*)d_in[3 * i + 1];
            R[i] = (const float*)d_in[3 * i + 2];
        } else {
            A[i] = (const float*)d_in[i];
            C[i] = (const float*)d_in[5 + i];
            R[i] = (const float*)d_in[10 + i];
        }
    }

    unsigned* keys   = (unsigned*)d_ws;
    unsigned* hist   = keys + NROWS;
    unsigned* coarse = hist + 4 * NBINS;
    unsigned* sel    = coarse + 4096;

    k_ruler<<<1530, 256, 0, stream>>>(C[0], C[1], C[2], C[3], keys, hist);
    k_hist<<<1024, 256, 0, stream>>>(keys, hist, coarse);
    k_select<<<4, 1024, 0, stream>>>(keys, hist, coarse, sel);
    k_epilogue<<<NSEL, 256, 0, stream>>>(A[0], A[1], A[2], A[3], A[4],
                                         C[0], C[1], C[2], C[3], C[4],
                                         R[0], R[1], R[2], R[3], R[4],
                                         sel, (float*)d_out);
}

// Round 13
// 85.398 us; speedup vs baseline: 1.1358x; 1.1358x over previous
//
#include <hip/hip_runtime.h>

#define CLS   160          // CLASS_NUM * NUM_PRED
#define TOPKN 1000
#define N0 147456
#define N1 36864
#define N2 9216
#define N3 2304
#define N4 576
#define NROWS (N0 + N1 + N2 + N3)
#define BD1 N0
#define BD2 (N0 + N1)
#define BD3 (N0 + N1 + N2)
#define NSEL (4 * TOPKN + N4)
#define NBINS 65536
#define CAND_CAP 2048

__device__ __forceinline__ unsigned sortable(float f) {
    unsigned u = __float_as_uint(f);
    return (u & 0x80000000u) ? ~u : (u | 0x80000000u);
}

// ---------------------------------------------------------------------------
// K1: ruler keys (proven R4-R6). Zeroes hist|coarse (contiguous).
// ---------------------------------------------------------------------------
__global__ __launch_bounds__(256) void k_ruler(
    const float* __restrict__ c0, const float* __restrict__ c1,
    const float* __restrict__ c2, const float* __restrict__ c3,
    unsigned* __restrict__ keys, unsigned* __restrict__ hist)
{
    int tid = blockIdx.x * 256 + threadIdx.x;
    if (tid < 4 * NBINS + 4096) hist[tid] = 0;

    int r0 = blockIdx.x << 7;
    const float* cb; int lr0;
    if (r0 < BD1)      { cb = c0; lr0 = r0; }
    else if (r0 < BD2) { cb = c1; lr0 = r0 - BD1; }
    else if (r0 < BD3) { cb = c2; lr0 = r0 - BD2; }
    else               { cb = c3; lr0 = r0 - BD3; }

    int wv   = threadIdx.x >> 6;
    int lane = threadIdx.x & 63;
    int sub  = lane >> 3;
    int col  = lane & 7;
    #pragma unroll
    for (int i = 0; i < 4; ++i) {
        int rrel = wv * 32 + i * 8 + sub;
        const float4* p = (const float4*)cb + (size_t)(lr0 + rrel) * 40 + col;
        float m = -3.4e38f;
        #pragma unroll
        for (int k = 0; k < 5; ++k) {
            float4 v = p[8 * k];
            m = fmaxf(m, fmaxf(fmaxf(v.x, v.y), fmaxf(v.z, v.w)));
        }
        m = fmaxf(m, __shfl_xor(m, 1));
        m = fmaxf(m, __shfl_xor(m, 2));
        m = fmaxf(m, __shfl_xor(m, 4));
        if (col == 0) keys[r0 + rrel] = sortable(m);
    }
}

// ---------------------------------------------------------------------------
// K2: chunked segment histogram (proven R4/R6). 1024 blocks x 256.
// ---------------------------------------------------------------------------
__global__ __launch_bounds__(256) void k_hist(const unsigned* __restrict__ keys,
                                              unsigned* __restrict__ hist,
                                              unsigned* __restrict__ coarse)
{
    int b        = blockIdx.x;
    int level    = b >> 8;
    unsigned seg = (b >> 4) & 15;
    int chunk    = b & 15;
    __shared__ unsigned cnt[4096];
    for (int i = threadIdx.x; i < 4096; i += 256) cnt[i] = 0;
    __syncthreads();
    int base, n;
    switch (level) {
        case 0:  base = 0;   n = N0; break;
        case 1:  base = BD1; n = N1; break;
        case 2:  base = BD2; n = N2; break;
        default: base = BD3; n = N3; break;
    }
    int q = n >> 4;
    const uint4* kp = (const uint4*)(keys + base + chunk * q);
    int nv = q >> 2;
    for (int i = threadIdx.x; i < nv; i += 256) {
        uint4 k = kp[i];
        unsigned b0 = k.x >> 16, b1 = k.y >> 16, b2 = k.z >> 16, b3 = k.w >> 16;
        if ((b0 >> 12) == seg) atomicAdd(&cnt[b0 & 4095u], 1u);
        if ((b1 >> 12) == seg) atomicAdd(&cnt[b1 & 4095u], 1u);
        if ((b2 >> 12) == seg) atomicAdd(&cnt[b2 & 4095u], 1u);
        if ((b3 >> 12) == seg) atomicAdd(&cnt[b3 & 4095u], 1u);
    }
    __syncthreads();
    unsigned* h = hist + level * NBINS + (seg << 12);
    for (int i = threadIdx.x; i < 4096; i += 256) {
        unsigned c = cnt[i];
        if (c) atomicAdd(&h[i], c);
    }
    if (threadIdx.x < 64) {
        int j = threadIdx.x;
        unsigned s2 = 0;
        #pragma unroll 8
        for (int i = 0; i < 64; ++i) s2 += cnt[j * 64 + ((i + j) & 63)];
        if (s2) atomicAdd(&coarse[level * 1024 + (int)(seg << 6) + j], s2);
    }
}

// ---------------------------------------------------------------------------
// K3: fused decide+compact+rank, one block per level. Parts A and B are
// R6-verbatim (the fastest measured variant, VGPR 12). Part C replaced:
// the O(C^2) rank was ~50us on this data — cnt caps at 2048, so 1024
// threads x 4096 uniform ds_read_b64 each = 65K wave-level LDS instrs
// saturating one CU's LDS pipe. Bitonic sort of the 2048 composites is 66
// stages x ~64 wave-level LDS instrs = 15x fewer; composites are unique so
// sorted position == exact lax.top_k rank (desc key, ties asc index).
// ---------------------------------------------------------------------------
__global__ __launch_bounds__(1024) void k_select(const unsigned* __restrict__ keys,
                                                 const unsigned* __restrict__ hist,
                                                 const unsigned* __restrict__ coarse,
                                                 unsigned* __restrict__ sel)
{
    int level = blockIdx.x;
    int t     = threadIdx.x;
    int lane  = t & 63;

    __shared__ unsigned s[1024];
    __shared__ unsigned long long a[CAND_CAP];
    __shared__ unsigned thr_s, chunk_s, cum0_s, cnt_s;

    // ---- A: threshold from coarse + one 64-bin refine (proven R6 math) ----
    s[t] = coarse[level * 1024 + t];
    if (t == 0) cnt_s = 0;
    __syncthreads();
    for (int off = 1; off < 1024; off <<= 1) {
        unsigned v   = s[t];
        unsigned add = (t + off < 1024) ? s[t + off] : 0u;
        __syncthreads();
        s[t] = v + add;
        __syncthreads();
    }
    if (s[t] >= TOPKN && (t == 1023 || s[t + 1] < TOPKN)) {
        chunk_s = (unsigned)t;
        cum0_s  = (t == 1023) ? 0u : s[t + 1];
    }
    __syncthreads();
    if (t < 64) {
        const unsigned* h = hist + level * NBINS;
        unsigned c = h[chunk_s * 64 + (unsigned)t];
        unsigned suf = c;
        #pragma unroll
        for (int off = 1; off < 64; off <<= 1) {
            unsigned v = __shfl_down(suf, off);
            if (t + off < 64) suf += v;
        }
        unsigned long long mask = __ballot(cum0_s + suf >= TOPKN);
        if (t == 0)
            thr_s = ((chunk_s << 6) + (63u - (unsigned)__clzll(mask))) << 16;
    }
    __syncthreads();
    unsigned thr = thr_s;

    // ---- B: simple streaming ballot-append (R6 verbatim — fastest) ----
    int base = (level == 0) ? 0 : (level == 1) ? BD1 : (level == 2) ? BD2 : BD3;
    int n    = (level == 0) ? N0 : (level == 1) ? N1 : (level == 2) ? N2 : N3;
    const uint4* kp = (const uint4*)(keys + base);
    int nv = n >> 2;
    for (int i = t; i < nv; i += 1024) {
        uint4 k4 = kp[i];
        unsigned kv[4] = {k4.x, k4.y, k4.z, k4.w};
        #pragma unroll
        for (int c = 0; c < 4; ++c) {
            bool pass = kv[c] >= thr;
            unsigned long long mask = __ballot(pass);
            if (pass) {
                int leader    = __ffsll((long long)mask) - 1;
                unsigned tot  = (unsigned)__popcll(mask);
                unsigned rank = (unsigned)__popcll(mask & ((1ull << lane) - 1ull));
                unsigned bp = 0;
                if (lane == leader) bp = atomicAdd(&cnt_s, tot);
                bp = (unsigned)__shfl((int)bp, leader);
                unsigned pos = bp + rank;
                if (pos < CAND_CAP)
                    a[pos] = ((unsigned long long)kv[c] << 32) |
                             (unsigned)~(unsigned)(4 * i + c);
            }
        }
    }
    __syncthreads();
    unsigned cnt = cnt_s;
    if (cnt > CAND_CAP) cnt = CAND_CAP;

    // ---- C: bitonic sort descending (position == exact rank) ----
    for (int i = t; i < CAND_CAP; i += 1024)
        if (i >= (int)cnt) a[i] = 0ull;          // pad sinks to the end
    __syncthreads();
    for (int k = 2; k <= CAND_CAP; k <<= 1) {
        for (int j = k >> 1; j > 0; j >>= 1) {
            #pragma unroll
            for (int e = 0; e < 2; ++e) {
                int i   = t + e * 1024;
                int ixj = i ^ j;
                if (ixj > i) {                    // each pair handled once
                    unsigned long long x = a[i], y = a[ixj];
                    bool desc = ((i & k) == 0);   // descending blocks
                    if (desc ? (x < y) : (x > y)) { a[i] = y; a[ixj] = x; }
                }
            }
            __syncthreads();
        }
    }
    if (t < TOPKN)
        sel[level * TOPKN + t] = ~(unsigned)(a[t] & 0xFFFFFFFFull);
}

// ---------------------------------------------------------------------------
// K4: epilogue (proven R6, unchanged). One block per selected anchor.
// ---------------------------------------------------------------------------
__global__ __launch_bounds__(256) void k_epilogue(
    const float* a0, const float* a1, const float* a2, const float* a3, const float* a4,
    const float* c0, const float* c1, const float* c2, const float* c3, const float* c4,
    const float* r0, const float* r1, const float* r2, const float* r3, const float* r4,
    const unsigned* __restrict__ sel, float* __restrict__ out)
{
    int s = blockIdx.x;
    int level, idx;
    if (s < 4 * TOPKN) {
        level = s / TOPKN;
        idx   = (int)sel[s];
    } else {
        level = 4;
        idx   = s - 4 * TOPKN;
    }
    const float *A, *C, *R;
    switch (level) {
        case 0: A = a0; C = c0; R = r0; break;
        case 1: A = a1; C = c1; R = r1; break;
        case 2: A = a2; C = c2; R = r2; break;
        case 3: A = a3; C = c3; R = r3; break;
        default: A = a4; C = c4; R = r4; break;
    }

    __shared__ float sc[CLS];
    __shared__ float bb[8];

    const float* cp = C + (size_t)idx * CLS;
    if (threadIdx.x < CLS) {
        float x = cp[threadIdx.x];
        sc[threadIdx.x] = 1.0f / (1.0f + __expf(-x));
    }
    if (threadIdx.x == 192) {
        const float* ap = A + (size_t)idx * 4;
        const float* rp = R + (size_t)idx * 8;
        float x1 = ap[0], y1 = ap[1], x2 = ap[2], y2 = ap[3];
        float w  = x2 - x1 + 1.0f, h = y2 - y1 + 1.0f;
        float cx = x1 + 0.5f * w,  cy = y1 + 0.5f * h;
        #pragma unroll
        for (int p = 0; p < 2; ++p) {
            float pcx = cx + rp[4 * p + 0] * w;
            float pcy = cy + rp[4 * p + 1] * h;
            float pw  = w * __expf(rp[4 * p + 2]);
            float ph  = h * __expf(rp[4 * p + 3]);
            bb[4 * p + 0] = pcx - 0.5f * pw;
            bb[4 * p + 1] = pcy - 0.5f * ph;
            bb[4 * p + 2] = pcx + 0.5f * pw;
            bb[4 * p + 3] = pcy + 0.5f * ph;
        }
    }
    __syncthreads();

    float4* orow = (float4*)(out + (size_t)s * 960);
    if (threadIdx.x < 240) {
        int j = threadIdx.x / 3, part = threadIdx.x % 3;
        float tag = (float)(j + 1);
        float4 v;
        if (part == 0)      v = make_float4(bb[0], bb[1], bb[2], bb[3]);
        else if (part == 1) v = make_float4(sc[j], tag, bb[4], bb[5]);
        else                v = make_float4(bb[6], bb[7], sc[80 + j], tag);
        orow[threadIdx.x] = v;
    }
}

// ---------------------------------------------------------------------------
// Workspace (uint32 words):
//   keys[NROWS] | hist[4*NBINS] | coarse[4096] | sel[4*TOPKN]  (~1.8 MB)
// hist|coarse zeroed by k_ruler each call.
// ---------------------------------------------------------------------------
extern "C" void kernel_launch(void* const* d_in, const int* in_sizes, int n_in,
                              void* d_out, int out_size, void* d_ws, size_t ws_size,
                              hipStream_t stream)
{
    bool interleaved = (in_sizes[1] > 1000000);
    const float *A[5], *C[5], *R[5];
    for (int i = 0; i < 5; ++i) {
        if (interleaved) {
            A[i] = (const float*)d_in[3 * i + 0];
            C[i] = (const float*)d_in[3 * i + 1];
            R[i] = (const float*)d_in[3 * i + 2];
        } else {
            A[i] = (const float*)d_in[i];
            C[i] = (const float*)d_in[5 + i];
            R[i] = (const float*)d_in[10 + i];
        }
    }

    unsigned* keys   = (unsigned*)d_ws;
    unsigned* hist   = keys + NROWS;
    unsigned* coarse = hist + 4 * NBINS;
    unsigned* sel    = coarse + 4096;

    k_ruler<<<1530, 256, 0, stream>>>(C[0], C[1], C[2], C[3], keys, hist);
    k_hist<<<1024, 256, 0, stream>>>(keys, hist, coarse);
    k_select<<<4, 1024, 0, stream>>>(keys, hist, coarse, sel);
    k_epilogue<<<NSEL, 256, 0, stream>>>(A[0], A[1], A[2], A[3], A[4],
                                         C[0], C[1], C[2], C[3], C[4],
                                         R[0], R[1], R[2], R[3], R[4],
                                         sel, (float*)d_out);
}